// Round 1
// baseline (754.482 us; speedup 1.0000x reference)
//
#include <hip/hip_runtime.h>
#include <hip/hip_bf16.h>

typedef __attribute__((ext_vector_type(8))) short short8;
typedef __attribute__((ext_vector_type(4))) float float4v;

__device__ __forceinline__ ushort f2bf(float f) {
    union { float f; unsigned u; } v; v.f = f;
    unsigned u = v.u;
    unsigned r = (u + 0x7fffu + ((u >> 16) & 1u)) >> 16;
    return (ushort)r;
}

// ---------------- cast x (fp32 -> bf16), vectorized ----------------
__global__ void cast_f32_bf16(const float* __restrict__ in, ushort* __restrict__ out, int n4) {
    int i = blockIdx.x * blockDim.x + threadIdx.x;
    if (i >= n4) return;
    float4 v = reinterpret_cast<const float4*>(in)[i];
    ushort4 o;
    o.x = f2bf(v.x); o.y = f2bf(v.y); o.z = f2bf(v.z); o.w = f2bf(v.w);
    reinterpret_cast<ushort4*>(out)[i] = o;
}

// ---------------- transpose + cast: in[R][C] fp32 -> out[C][R] bf16 ----------------
__global__ void transpose_cast(const float* __restrict__ in, ushort* __restrict__ out, int R, int C) {
    int idx = blockIdx.x * blockDim.x + threadIdx.x;
    if (idx >= R * C) return;
    int r = idx / C, c = idx - r * C;
    out[(size_t)c * R + r] = f2bf(in[idx]);
}

// ---------------- GEMM1: qkv = xb @ w_qkv ----------------
// xb [16384][1024] bf16, wT [384][1024] bf16 (B^T layout)
// writes Q [16384][128], K [16384][128] row-major; V transposed Vt[b][128][4096]
__global__ __launch_bounds__(256) void gemm_qkv(const ushort* __restrict__ xb,
                                                const ushort* __restrict__ wT,
                                                ushort* __restrict__ Qm,
                                                ushort* __restrict__ Km,
                                                ushort* __restrict__ Vt) {
    const int lane = threadIdx.x & 63;
    const int w = threadIdx.x >> 6;
    const int row16 = lane & 15, grp = lane >> 4;
    const int mt = blockIdx.x * 16;
    const int n16 = (blockIdx.y * 4 + w) * 16;   // 0..368
    const ushort* arow = xb + (size_t)(mt + row16) * 1024 + grp * 8;
    const ushort* brow = wT + (size_t)(n16 + row16) * 1024 + grp * 8;
    float4v acc = {0.f, 0.f, 0.f, 0.f};
#pragma unroll 8
    for (int ks = 0; ks < 32; ++ks) {
        short8 af = *reinterpret_cast<const short8*>(arow + ks * 32);
        short8 bf = *reinterpret_cast<const short8*>(brow + ks * 32);
        acc = __builtin_amdgcn_mfma_f32_16x16x32_bf16(af, bf, acc, 0, 0, 0);
    }
    const int col = n16 + row16;
#pragma unroll
    for (int i = 0; i < 4; ++i) {
        int row = mt + grp * 4 + i;
        ushort hv = f2bf(acc[i]);
        if (col < 128) {
            Qm[(size_t)row * 128 + col] = hv;
        } else if (col < 256) {
            Km[(size_t)row * 128 + (col - 128)] = hv;
        } else {
            int d = col - 256, b = row >> 12, t = row & 4095;
            Vt[((size_t)b * 128 + d) * 4096 + t] = hv;
        }
    }
}

// ---------------- flash attention (causal), 1 wave / 16 q-rows ----------------
__global__ __launch_bounds__(64) void attn_kernel(const ushort* __restrict__ Qm,
                                                  const ushort* __restrict__ Km,
                                                  const ushort* __restrict__ Vt,
                                                  ushort* __restrict__ O) {
    __shared__ ushort plds[16][72];   // padded to break bank conflicts
    const int lane = threadIdx.x;
    const int row16 = lane & 15, grp = lane >> 4;
    const int qt = blockIdx.x * 16;
    const int b = blockIdx.y;

    const ushort* qb = Qm + ((size_t)(b * 4096 + qt + row16)) * 128 + grp * 8;
    short8 qf[4];
#pragma unroll
    for (int kk = 0; kk < 4; ++kk) qf[kk] = *reinterpret_cast<const short8*>(qb + kk * 32);

    float4v o[8];
#pragma unroll
    for (int dt = 0; dt < 8; ++dt) o[dt] = (float4v){0.f, 0.f, 0.f, 0.f};
    float mrun[4], lrun[4];
#pragma unroll
    for (int i = 0; i < 4; ++i) { mrun[i] = -3e38f; lrun[i] = 0.f; }

    const int lastkvt = (qt >> 6) << 6;
    const ushort* kbase = Km + (size_t)b * 4096 * 128;
    const ushort* vbase = Vt + (size_t)b * 128 * 4096;

    for (int kvt = 0; kvt <= lastkvt; kvt += 64) {
        float s[4][4];
#pragma unroll
        for (int ct = 0; ct < 4; ++ct) {
            float4v acc = {0.f, 0.f, 0.f, 0.f};
            const ushort* kr = kbase + (size_t)(kvt + ct * 16 + row16) * 128 + grp * 8;
#pragma unroll
            for (int kk = 0; kk < 4; ++kk) {
                short8 kf = *reinterpret_cast<const short8*>(kr + kk * 32);
                acc = __builtin_amdgcn_mfma_f32_16x16x32_bf16(qf[kk], kf, acc, 0, 0, 0);
            }
#pragma unroll
            for (int i = 0; i < 4; ++i) s[ct][i] = acc[i] * 0.03125f;
        }
        if (kvt == lastkvt) {
#pragma unroll
            for (int ct = 0; ct < 4; ++ct) {
                int kcol = kvt + ct * 16 + row16;
#pragma unroll
                for (int i = 0; i < 4; ++i) {
                    int q = qt + grp * 4 + i;
                    if (kcol > q) s[ct][i] = -3e38f;
                }
            }
        }
        // online softmax (row r = grp*4+i lives in the 16 lanes of this grp)
        float scale_f[4];
#pragma unroll
        for (int i = 0; i < 4; ++i) {
            float tm = fmaxf(fmaxf(s[0][i], s[1][i]), fmaxf(s[2][i], s[3][i]));
#pragma unroll
            for (int msk = 1; msk < 16; msk <<= 1) tm = fmaxf(tm, __shfl_xor(tm, msk));
            float mnew = fmaxf(mrun[i], tm);
            scale_f[i] = __expf(mrun[i] - mnew);
            float psum = 0.f;
#pragma unroll
            for (int ct = 0; ct < 4; ++ct) {
                float p = __expf(s[ct][i] - mnew);
                s[ct][i] = p;
                psum += p;
            }
#pragma unroll
            for (int msk = 1; msk < 16; msk <<= 1) psum += __shfl_xor(psum, msk);
            lrun[i] = lrun[i] * scale_f[i] + psum;
            mrun[i] = mnew;
        }
#pragma unroll
        for (int dt = 0; dt < 8; ++dt)
#pragma unroll
            for (int i = 0; i < 4; ++i) o[dt][i] *= scale_f[i];
        // P -> LDS (D-layout -> A-layout round trip)
#pragma unroll
        for (int ct = 0; ct < 4; ++ct)
#pragma unroll
            for (int i = 0; i < 4; ++i)
                plds[grp * 4 + i][ct * 16 + row16] = f2bf(s[ct][i]);
        __syncthreads();
        // PV: A = P[16][64], B = V[64][128] via Vt rows
#pragma unroll
        for (int kk2 = 0; kk2 < 2; ++kk2) {
            short8 pa = *reinterpret_cast<const short8*>(&plds[row16][kk2 * 32 + grp * 8]);
#pragma unroll
            for (int dt = 0; dt < 8; ++dt) {
                const ushort* vr = vbase + (size_t)(dt * 16 + row16) * 4096 + kvt + kk2 * 32 + grp * 8;
                short8 vf = *reinterpret_cast<const short8*>(vr);
                o[dt] = __builtin_amdgcn_mfma_f32_16x16x32_bf16(pa, vf, o[dt], 0, 0, 0);
            }
        }
        __syncthreads();
    }
    // epilogue: O[b*4096+qt+grp*4+i][dt*16+row16] = o/l
#pragma unroll
    for (int i = 0; i < 4; ++i) {
        float inv = 1.f / lrun[i];
        size_t row = (size_t)(b * 4096 + qt + grp * 4 + i);
#pragma unroll
        for (int dt = 0; dt < 8; ++dt)
            O[row * 128 + dt * 16 + row16] = f2bf(o[dt][i] * inv);
    }
}

// ---------------- GEMM2: out = AO @ w_out + b_out ----------------
// AO [16384][128] bf16, wT [1024][128] bf16 (B^T layout), out fp32 [16384][1024]
__global__ __launch_bounds__(256) void gemm_out(const ushort* __restrict__ AO,
                                                const ushort* __restrict__ wT,
                                                const float* __restrict__ bias,
                                                float* __restrict__ out) {
    const int lane = threadIdx.x & 63;
    const int w = threadIdx.x >> 6;
    const int row16 = lane & 15, grp = lane >> 4;
    const int mt = blockIdx.x * 16;
    const int n16 = (blockIdx.y * 4 + w) * 16;
    const ushort* ar = AO + (size_t)(mt + row16) * 128 + grp * 8;
    const ushort* br = wT + (size_t)(n16 + row16) * 128 + grp * 8;
    float4v acc = {0.f, 0.f, 0.f, 0.f};
#pragma unroll
    for (int ks = 0; ks < 4; ++ks) {
        short8 af = *reinterpret_cast<const short8*>(ar + ks * 32);
        short8 bf = *reinterpret_cast<const short8*>(br + ks * 32);
        acc = __builtin_amdgcn_mfma_f32_16x16x32_bf16(af, bf, acc, 0, 0, 0);
    }
    const int col = n16 + row16;
    const float bv = bias[col];
#pragma unroll
    for (int i = 0; i < 4; ++i) {
        int row = mt + grp * 4 + i;
        out[(size_t)row * 1024 + col] = acc[i] + bv;
    }
}

extern "C" void kernel_launch(void* const* d_in, const int* in_sizes, int n_in,
                              void* d_out, int out_size, void* d_ws, size_t ws_size,
                              hipStream_t stream) {
    const float* x     = (const float*)d_in[0];   // [4,4096,1024]
    const float* w_qkv = (const float*)d_in[1];   // [1024,384]
    const float* w_out = (const float*)d_in[2];   // [128,1024]
    const float* b_out = (const float*)d_in[3];   // [1024]
    float* out = (float*)d_out;

    char* ws = (char*)d_ws;
    ushort* xb    = (ushort*)(ws);                 // 33,554,432 B
    ushort* wqkvT = (ushort*)(ws + 33554432);      //    786,432 B
    ushort* woutT = (ushort*)(ws + 34340864);      //    262,144 B
    ushort* Qm    = (ushort*)(ws + 34603008);      //  4,194,304 B
    ushort* Km    = (ushort*)(ws + 38797312);      //  4,194,304 B
    ushort* Vt    = (ushort*)(ws + 42991616);      //  4,194,304 B
    ushort* AO    = (ushort*)(ws + 47185920);      //  4,194,304 B  (total ~51.4 MB)

    // casts
    {
        int n4 = (4 * 4096 * 1024) / 4;
        cast_f32_bf16<<<dim3((n4 + 255) / 256), dim3(256), 0, stream>>>(x, xb, n4);
    }
    transpose_cast<<<dim3((1024 * 384 + 255) / 256), dim3(256), 0, stream>>>(w_qkv, wqkvT, 1024, 384);
    transpose_cast<<<dim3((128 * 1024 + 255) / 256), dim3(256), 0, stream>>>(w_out, woutT, 128, 1024);

    // QKV projection
    gemm_qkv<<<dim3(1024, 6), dim3(256), 0, stream>>>(xb, wqkvT, Qm, Km, Vt);

    // causal flash attention
    attn_kernel<<<dim3(256, 4), dim3(64), 0, stream>>>(Qm, Km, Vt, AO);

    // output projection + bias
    gemm_out<<<dim3(1024, 16), dim3(256), 0, stream>>>(AO, woutT, b_out, out);
}

// Round 2
// 370.592 us; speedup vs baseline: 2.0359x; 2.0359x over previous
//
#include <hip/hip_runtime.h>
#include <hip/hip_bf16.h>

typedef __attribute__((ext_vector_type(8))) short short8;
typedef __attribute__((ext_vector_type(4))) float float4v;

__device__ __forceinline__ ushort f2bf(float f) {
    union { float f; unsigned u; } v; v.f = f;
    unsigned u = v.u;
    unsigned r = (u + 0x7fffu + ((u >> 16) & 1u)) >> 16;
    return (ushort)r;
}

// ---------------- cast x (fp32 -> bf16), vectorized ----------------
__global__ void cast_f32_bf16(const float* __restrict__ in, ushort* __restrict__ out, int n4) {
    int i = blockIdx.x * blockDim.x + threadIdx.x;
    if (i >= n4) return;
    float4 v = reinterpret_cast<const float4*>(in)[i];
    ushort4 o;
    o.x = f2bf(v.x); o.y = f2bf(v.y); o.z = f2bf(v.z); o.w = f2bf(v.w);
    reinterpret_cast<ushort4*>(out)[i] = o;
}

// ---------------- transpose + cast: in[R][C] fp32 -> out[C][R] bf16 ----------------
__global__ void transpose_cast(const float* __restrict__ in, ushort* __restrict__ out, int R, int C) {
    int idx = blockIdx.x * blockDim.x + threadIdx.x;
    if (idx >= R * C) return;
    int r = idx / C, c = idx - r * C;
    out[(size_t)c * R + r] = f2bf(in[idx]);
}

// ---------------- GEMM1: qkv = xb @ w_qkv ----------------
__global__ __launch_bounds__(256) void gemm_qkv(const ushort* __restrict__ xb,
                                                const ushort* __restrict__ wT,
                                                ushort* __restrict__ Qm,
                                                ushort* __restrict__ Km,
                                                ushort* __restrict__ Vt) {
    const int lane = threadIdx.x & 63;
    const int w = threadIdx.x >> 6;
    const int row16 = lane & 15, grp = lane >> 4;
    const int mt = blockIdx.x * 16;
    const int n16 = (blockIdx.y * 4 + w) * 16;   // 0..368
    const ushort* arow = xb + (size_t)(mt + row16) * 1024 + grp * 8;
    const ushort* brow = wT + (size_t)(n16 + row16) * 1024 + grp * 8;
    float4v acc = {0.f, 0.f, 0.f, 0.f};
#pragma unroll 8
    for (int ks = 0; ks < 32; ++ks) {
        short8 af = *reinterpret_cast<const short8*>(arow + ks * 32);
        short8 bf = *reinterpret_cast<const short8*>(brow + ks * 32);
        acc = __builtin_amdgcn_mfma_f32_16x16x32_bf16(af, bf, acc, 0, 0, 0);
    }
    const int col = n16 + row16;
#pragma unroll
    for (int i = 0; i < 4; ++i) {
        int row = mt + grp * 4 + i;
        ushort hv = f2bf(acc[i]);
        if (col < 128) {
            Qm[(size_t)row * 128 + col] = hv;
        } else if (col < 256) {
            Km[(size_t)row * 128 + (col - 128)] = hv;
        } else {
            int d = col - 256, b = row >> 12, t = row & 4095;
            Vt[((size_t)b * 128 + d) * 4096 + t] = hv;
        }
    }
}

// ---------------- flash attention with KV-split (causal) ----------------
// 1 wave / 32 q-rows / 1 of 4 KV splits. Writes unnormalized partial O (fp32),
// running max M and denom L per row. Combine kernel merges the 4 splits.
__global__ __launch_bounds__(64) void attn_split(const ushort* __restrict__ Qm,
                                                 const ushort* __restrict__ Km,
                                                 const ushort* __restrict__ Vt,
                                                 float* __restrict__ Opart,
                                                 float* __restrict__ Mpart,
                                                 float* __restrict__ Lpart) {
    __shared__ ushort plds[32][72];
    const int lane = threadIdx.x;
    const int row16 = lane & 15, grp = lane >> 4;
    const int qtile = 127 - blockIdx.x;          // reversed: biggest work first
    const int s = blockIdx.y;
    const int b = blockIdx.z;
    const int qt0 = qtile * 32;
    const int ext_tiles = (qt0 + 32 + 63) >> 6;  // #64-key KV tiles in causal extent
    const int t0 = (s * ext_tiles) >> 2;
    const int t1 = ((s + 1) * ext_tiles) >> 2;

    const size_t pbase = (((size_t)b * 128 + qtile) * 4 + s);
    float* mlM = Mpart + pbase * 32;
    float* mlL = Lpart + pbase * 32;

    if (t0 >= t1) {                              // empty split
        if (lane < 32) { mlM[lane] = -1e30f; mlL[lane] = 0.f; }
        return;
    }

    const ushort* qb = Qm + ((size_t)(b * 4096 + qt0 + row16)) * 128 + grp * 8;
    short8 qf[2][4];
#pragma unroll
    for (int rt = 0; rt < 2; ++rt)
#pragma unroll
        for (int kk = 0; kk < 4; ++kk)
            qf[rt][kk] = *reinterpret_cast<const short8*>(qb + rt * 16 * 128 + kk * 32);

    float4v o[2][8];
#pragma unroll
    for (int rt = 0; rt < 2; ++rt)
#pragma unroll
        for (int dt = 0; dt < 8; ++dt) o[rt][dt] = (float4v){0.f, 0.f, 0.f, 0.f};
    float mrun[2][4], lrun[2][4];
#pragma unroll
    for (int rt = 0; rt < 2; ++rt)
#pragma unroll
        for (int i = 0; i < 4; ++i) { mrun[rt][i] = -1e30f; lrun[rt][i] = 0.f; }

    const ushort* kbase = Km + (size_t)b * 4096 * 128;
    const ushort* vbase = Vt + (size_t)b * 128 * 4096;

    for (int t = t0; t < t1; ++t) {
        const int kvt = t * 64;
        // ---- batch-load ALL 16 K fragments (16 loads in flight) ----
        short8 kf[4][4];
#pragma unroll
        for (int ct = 0; ct < 4; ++ct) {
            const ushort* kr = kbase + (size_t)(kvt + ct * 16 + row16) * 128 + grp * 8;
#pragma unroll
            for (int kk = 0; kk < 4; ++kk)
                kf[ct][kk] = *reinterpret_cast<const short8*>(kr + kk * 32);
        }
        // ---- QK^T: 32 MFMAs, each K fragment feeds both row-tiles ----
        float4v a[2][4];
#pragma unroll
        for (int rt = 0; rt < 2; ++rt)
#pragma unroll
            for (int ct = 0; ct < 4; ++ct) a[rt][ct] = (float4v){0.f, 0.f, 0.f, 0.f};
#pragma unroll
        for (int ct = 0; ct < 4; ++ct)
#pragma unroll
            for (int kk = 0; kk < 4; ++kk) {
                a[0][ct] = __builtin_amdgcn_mfma_f32_16x16x32_bf16(qf[0][kk], kf[ct][kk], a[0][ct], 0, 0, 0);
                a[1][ct] = __builtin_amdgcn_mfma_f32_16x16x32_bf16(qf[1][kk], kf[ct][kk], a[1][ct], 0, 0, 0);
            }
        // ---- issue ALL 16 V fragment loads now; softmax latency covers them ----
        short8 vf[2][8];
#pragma unroll
        for (int kk2 = 0; kk2 < 2; ++kk2)
#pragma unroll
            for (int dt = 0; dt < 8; ++dt)
                vf[kk2][dt] = *reinterpret_cast<const short8*>(
                    vbase + (size_t)(dt * 16 + row16) * 4096 + kvt + kk2 * 32 + grp * 8);

        float sc[2][4][4];
#pragma unroll
        for (int rt = 0; rt < 2; ++rt)
#pragma unroll
            for (int ct = 0; ct < 4; ++ct)
#pragma unroll
                for (int i = 0; i < 4; ++i) sc[rt][ct][i] = a[rt][ct][i] * 0.03125f;

        if (kvt + 63 > qt0) {                    // causal mask needed
#pragma unroll
            for (int ct = 0; ct < 4; ++ct) {
                int kcol = kvt + ct * 16 + row16;
#pragma unroll
                for (int rt = 0; rt < 2; ++rt)
#pragma unroll
                    for (int i = 0; i < 4; ++i) {
                        int q = qt0 + rt * 16 + grp * 4 + i;
                        if (kcol > q) sc[rt][ct][i] = -3e38f;
                    }
            }
        }
        // ---- online softmax per (rt,i) row-slot ----
        float scale_f[2][4];
#pragma unroll
        for (int rt = 0; rt < 2; ++rt)
#pragma unroll
            for (int i = 0; i < 4; ++i) {
                float tm = fmaxf(fmaxf(sc[rt][0][i], sc[rt][1][i]), fmaxf(sc[rt][2][i], sc[rt][3][i]));
#pragma unroll
                for (int msk = 1; msk < 16; msk <<= 1) tm = fmaxf(tm, __shfl_xor(tm, msk));
                float mnew = fmaxf(fmaxf(mrun[rt][i], tm), -1e30f);
                scale_f[rt][i] = __expf(mrun[rt][i] - mnew);
                float psum = 0.f;
#pragma unroll
                for (int ct = 0; ct < 4; ++ct) {
                    float p = __expf(sc[rt][ct][i] - mnew);
                    sc[rt][ct][i] = p;
                    psum += p;
                }
#pragma unroll
                for (int msk = 1; msk < 16; msk <<= 1) psum += __shfl_xor(psum, msk);
                lrun[rt][i] = lrun[rt][i] * scale_f[rt][i] + psum;
                mrun[rt][i] = mnew;
            }
#pragma unroll
        for (int rt = 0; rt < 2; ++rt)
#pragma unroll
            for (int dt = 0; dt < 8; ++dt)
#pragma unroll
                for (int i = 0; i < 4; ++i) o[rt][dt][i] *= scale_f[rt][i];
        // ---- P -> LDS (D-layout -> A-layout) ----
#pragma unroll
        for (int rt = 0; rt < 2; ++rt)
#pragma unroll
            for (int ct = 0; ct < 4; ++ct)
#pragma unroll
                for (int i = 0; i < 4; ++i)
                    plds[rt * 16 + grp * 4 + i][ct * 16 + row16] = f2bf(sc[rt][ct][i]);
        __syncthreads();
        // ---- PV: 32 MFMAs, each V fragment feeds both row-tiles ----
#pragma unroll
        for (int kk2 = 0; kk2 < 2; ++kk2) {
            short8 pa0 = *reinterpret_cast<const short8*>(&plds[row16][kk2 * 32 + grp * 8]);
            short8 pa1 = *reinterpret_cast<const short8*>(&plds[16 + row16][kk2 * 32 + grp * 8]);
#pragma unroll
            for (int dt = 0; dt < 8; ++dt) {
                o[0][dt] = __builtin_amdgcn_mfma_f32_16x16x32_bf16(pa0, vf[kk2][dt], o[0][dt], 0, 0, 0);
                o[1][dt] = __builtin_amdgcn_mfma_f32_16x16x32_bf16(pa1, vf[kk2][dt], o[1][dt], 0, 0, 0);
            }
        }
        __syncthreads();
    }
    // ---- write partial (unnormalized O, running m, denom l) ----
    float* ob = Opart + pbase * 32 * 128;
#pragma unroll
    for (int rt = 0; rt < 2; ++rt)
#pragma unroll
        for (int i = 0; i < 4; ++i) {
            int r = rt * 16 + grp * 4 + i;
#pragma unroll
            for (int dt = 0; dt < 8; ++dt)
                ob[(size_t)r * 128 + dt * 16 + row16] = o[rt][dt][i];
        }
    if (row16 == 0) {
#pragma unroll
        for (int rt = 0; rt < 2; ++rt)
#pragma unroll
            for (int i = 0; i < 4; ++i) {
                mlM[rt * 16 + grp * 4 + i] = mrun[rt][i];
                mlL[rt * 16 + grp * 4 + i] = lrun[rt][i];
            }
    }
}

// ---------------- combine the 4 KV splits (LSE merge) ----------------
__global__ __launch_bounds__(128) void attn_combine(const float* __restrict__ Opart,
                                                    const float* __restrict__ Mpart,
                                                    const float* __restrict__ Lpart,
                                                    ushort* __restrict__ AO) {
    const int row = blockIdx.x;                  // 0..16383
    const int b = row >> 12, t = row & 4095;
    const int qtile = t >> 5, r = t & 31;
    const size_t sb = (((size_t)b * 128 + qtile) * 4);
    float m[4], l[4];
#pragma unroll
    for (int s = 0; s < 4; ++s) {
        m[s] = Mpart[(sb + s) * 32 + r];
        l[s] = Lpart[(sb + s) * 32 + r];
    }
    float M = fmaxf(fmaxf(m[0], m[1]), fmaxf(m[2], m[3]));
    float w[4], denom = 0.f;
#pragma unroll
    for (int s = 0; s < 4; ++s) {
        w[s] = __expf(m[s] - M);
        denom += w[s] * l[s];
    }
    const int col = threadIdx.x;
    float acc = 0.f;
#pragma unroll
    for (int s = 0; s < 4; ++s) {
        if (w[s] > 0.f)
            acc += w[s] * Opart[((sb + s) * 32 + r) * 128 + col];
    }
    AO[(size_t)row * 128 + col] = f2bf(acc / denom);
}

// ---------------- GEMM2: out = AO @ w_out + b_out ----------------
__global__ __launch_bounds__(256) void gemm_out(const ushort* __restrict__ AO,
                                                const ushort* __restrict__ wT,
                                                const float* __restrict__ bias,
                                                float* __restrict__ out) {
    const int lane = threadIdx.x & 63;
    const int w = threadIdx.x >> 6;
    const int row16 = lane & 15, grp = lane >> 4;
    const int mt = blockIdx.x * 16;
    const int n16 = (blockIdx.y * 4 + w) * 16;
    const ushort* ar = AO + (size_t)(mt + row16) * 128 + grp * 8;
    const ushort* br = wT + (size_t)(n16 + row16) * 128 + grp * 8;
    float4v acc = {0.f, 0.f, 0.f, 0.f};
#pragma unroll
    for (int ks = 0; ks < 4; ++ks) {
        short8 af = *reinterpret_cast<const short8*>(ar + ks * 32);
        short8 bf = *reinterpret_cast<const short8*>(br + ks * 32);
        acc = __builtin_amdgcn_mfma_f32_16x16x32_bf16(af, bf, acc, 0, 0, 0);
    }
    const int col = n16 + row16;
    const float bv = bias[col];
#pragma unroll
    for (int i = 0; i < 4; ++i) {
        int row = mt + grp * 4 + i;
        out[(size_t)row * 1024 + col] = acc[i] + bv;
    }
}

extern "C" void kernel_launch(void* const* d_in, const int* in_sizes, int n_in,
                              void* d_out, int out_size, void* d_ws, size_t ws_size,
                              hipStream_t stream) {
    const float* x     = (const float*)d_in[0];   // [4,4096,1024]
    const float* w_qkv = (const float*)d_in[1];   // [1024,384]
    const float* w_out = (const float*)d_in[2];   // [128,1024]
    const float* b_out = (const float*)d_in[3];   // [1024]
    float* out = (float*)d_out;

    char* ws = (char*)d_ws;
    ushort* xb    = (ushort*)(ws);                 // 33,554,432 B (dead after gemm_qkv)
    ushort* wqkvT = (ushort*)(ws + 33554432);      //    786,432 B
    ushort* woutT = (ushort*)(ws + 34340864);      //    262,144 B
    ushort* Qm    = (ushort*)(ws + 34603008);      //  4,194,304 B
    ushort* Km    = (ushort*)(ws + 38797312);      //  4,194,304 B
    ushort* Vt    = (ushort*)(ws + 42991616);      //  4,194,304 B
    ushort* AO    = (ushort*)(ws + 47185920);      //  4,194,304 B
    float* Opart  = (float*)(ws);                  // alias xb: 4*128*4*32*128*4 = 33,554,432 B
    float* Mpart  = (float*)(ws + 51380224);       //    262,144 B
    float* Lpart  = (float*)(ws + 51642368);       //    262,144 B  (total ~51.9 MB)

    // casts
    {
        int n4 = (4 * 4096 * 1024) / 4;
        cast_f32_bf16<<<dim3((n4 + 255) / 256), dim3(256), 0, stream>>>(x, xb, n4);
    }
    transpose_cast<<<dim3((1024 * 384 + 255) / 256), dim3(256), 0, stream>>>(w_qkv, wqkvT, 1024, 384);
    transpose_cast<<<dim3((128 * 1024 + 255) / 256), dim3(256), 0, stream>>>(w_out, woutT, 128, 1024);

    // QKV projection
    gemm_qkv<<<dim3(1024, 6), dim3(256), 0, stream>>>(xb, wqkvT, Qm, Km, Vt);

    // causal flash attention, 4-way KV split + combine
    attn_split<<<dim3(128, 4, 4), dim3(64), 0, stream>>>(Qm, Km, Vt, Opart, Mpart, Lpart);
    attn_combine<<<dim3(16384), dim3(128), 0, stream>>>(Opart, Mpart, Lpart, AO);

    // output projection + bias
    gemm_out<<<dim3(1024, 16), dim3(256), 0, stream>>>(AO, woutT, b_out, out);
}

// Round 3
// 182.510 us; speedup vs baseline: 4.1339x; 2.0305x over previous
//
#include <hip/hip_runtime.h>
#include <hip/hip_bf16.h>

typedef __attribute__((ext_vector_type(8))) short short8;
typedef __attribute__((ext_vector_type(4))) float float4v;

#define AS1(p) ((const __attribute__((address_space(1))) void*)(p))
#define AS3(p) ((__attribute__((address_space(3))) void*)(p))

__device__ __forceinline__ ushort f2bf(float f) {
    union { float f; unsigned u; } v; v.f = f;
    unsigned u = v.u;
    unsigned r = (u + 0x7fffu + ((u >> 16) & 1u)) >> 16;
    return (ushort)r;
}

// ---------------- cast x (fp32 -> bf16), vectorized ----------------
__global__ void cast_f32_bf16(const float* __restrict__ in, ushort* __restrict__ out, int n4) {
    int i = blockIdx.x * blockDim.x + threadIdx.x;
    if (i >= n4) return;
    float4 v = reinterpret_cast<const float4*>(in)[i];
    ushort4 o;
    o.x = f2bf(v.x); o.y = f2bf(v.y); o.z = f2bf(v.z); o.w = f2bf(v.w);
    reinterpret_cast<ushort4*>(out)[i] = o;
}

// ---------------- transpose + cast: in[R][C] fp32 -> out[C][R] bf16 ----------------
__global__ void transpose_cast(const float* __restrict__ in, ushort* __restrict__ out, int R, int C) {
    int idx = blockIdx.x * blockDim.x + threadIdx.x;
    if (idx >= R * C) return;
    int r = idx / C, c = idx - r * C;
    out[(size_t)c * R + r] = f2bf(in[idx]);
}

// ======================= tiled GEMM core (m97 structure) =======================
// 128x128 tile, BK=64, 256 threads (4 waves, 2x2), global_load_lds staging with
// XOR-swizzled (pre-swizzled-source) LDS layout. A [M][K], B^T [N][K], both bf16.

// stage a 128x64 bf16 tile: gbase = tile origin, ld = row stride (elements)
__device__ __forceinline__ void stage128x64(const ushort* gbase, int ld, ushort* lds, int tid) {
    const int wavebase = tid & 192;             // wave_id * 64
#pragma unroll
    for (int j = 0; j < 4; ++j) {
        int idx = j * 256 + tid;
        int row = idx >> 3;
        int slot = idx & 7;
        int s = slot ^ (row & 7);               // inverse-swizzled source chunk
        const ushort* g = gbase + (size_t)row * ld + s * 8;
        int ldsoff = (j * 256 + wavebase) * 16; // bytes, wave-uniform
        __builtin_amdgcn_global_load_lds(AS1(g), AS3((char*)lds + ldsoff), 16, 0, 0);
    }
}

// one BK=64 step: 16 swizzled ds_read_b128 + 32 MFMA
__device__ __forceinline__ void compute64(const ushort* As, const ushort* Bs,
                                          int wr, int wc, int row16, int grp,
                                          float4v acc[4][4]) {
    const char* Ab = (const char*)As;
    const char* Bb = (const char*)Bs;
#pragma unroll
    for (int kk = 0; kk < 2; ++kk) {
        short8 a[4], b[4];
        const int sw = row16 & 7;
#pragma unroll
        for (int m = 0; m < 4; ++m)
            a[m] = *(const short8*)(Ab + (wr * 64 + m * 16 + row16) * 128 + (((kk * 4 + grp) ^ sw) << 4));
#pragma unroll
        for (int n = 0; n < 4; ++n)
            b[n] = *(const short8*)(Bb + (wc * 64 + n * 16 + row16) * 128 + (((kk * 4 + grp) ^ sw) << 4));
#pragma unroll
        for (int m = 0; m < 4; ++m)
#pragma unroll
            for (int n = 0; n < 4; ++n)
                acc[m][n] = __builtin_amdgcn_mfma_f32_16x16x32_bf16(a[m], b[n], acc[m][n], 0, 0, 0);
    }
}

// ---------------- GEMM1: qkv = xb @ w_qkv; writes Q,K,Vrow row-major ----------------
__global__ __launch_bounds__(256) void gemm_qkv(const ushort* __restrict__ xb,
                                                const ushort* __restrict__ wT,
                                                ushort* __restrict__ Qm,
                                                ushort* __restrict__ Km,
                                                ushort* __restrict__ Vrow) {
    __shared__ ushort As[128 * 64];
    __shared__ ushort Bs[128 * 64];
    const int tid = threadIdx.x;
    const int lane = tid & 63, w = tid >> 6;
    const int row16 = lane & 15, grp = lane >> 4;
    const int wr = w >> 1, wc = w & 1;
    const int mt = blockIdx.x * 128;
    const int by = blockIdx.y;                   // 0:Q 1:K 2:V
    const int n0 = by * 128;

    float4v acc[4][4];
#pragma unroll
    for (int m = 0; m < 4; ++m)
#pragma unroll
        for (int n = 0; n < 4; ++n) acc[m][n] = (float4v){0.f, 0.f, 0.f, 0.f};

    for (int kt = 0; kt < 1024; kt += 64) {
        stage128x64(xb + (size_t)mt * 1024 + kt, 1024, As, tid);
        stage128x64(wT + (size_t)n0 * 1024 + kt, 1024, Bs, tid);
        __syncthreads();
        compute64(As, Bs, wr, wc, row16, grp, acc);
        __syncthreads();
    }

    ushort* dst = (by == 0) ? Qm : (by == 1) ? Km : Vrow;
#pragma unroll
    for (int m = 0; m < 4; ++m)
#pragma unroll
        for (int i = 0; i < 4; ++i) {
            int row = mt + wr * 64 + m * 16 + grp * 4 + i;
#pragma unroll
            for (int n = 0; n < 4; ++n) {
                int coll = wc * 64 + n * 16 + row16;
                dst[(size_t)row * 128 + coll] = f2bf(acc[m][n][i]);
            }
        }
}

// ---------------- V transpose: Vrow[b*4096+t][128] -> Vt[b][128][4096] ----------------
__global__ __launch_bounds__(256) void v_transpose(const ushort* __restrict__ Vrow,
                                                   ushort* __restrict__ Vt) {
    __shared__ ushort tile[32][34];
    const int tx = threadIdx.x & 31, ty = threadIdx.x >> 5;   // 32 x 8
    const int t0 = blockIdx.x * 32, d0 = blockIdx.y * 32, b = blockIdx.z;
    const ushort* src = Vrow + ((size_t)(b * 4096 + t0)) * 128 + d0;
#pragma unroll
    for (int j = 0; j < 4; ++j)
        tile[ty * 4 + j][tx] = src[(size_t)(ty * 4 + j) * 128 + tx];
    __syncthreads();
    ushort* dst = Vt + ((size_t)(b * 128 + d0)) * 4096 + t0;
#pragma unroll
    for (int j = 0; j < 4; ++j)
        dst[(size_t)(ty * 4 + j) * 4096 + tx] = tile[tx][ty * 4 + j];
}

// ---------------- flash attention with KV-split (causal) ----------------
__global__ __launch_bounds__(64) void attn_split(const ushort* __restrict__ Qm,
                                                 const ushort* __restrict__ Km,
                                                 const ushort* __restrict__ Vt,
                                                 float* __restrict__ Opart,
                                                 float* __restrict__ Mpart,
                                                 float* __restrict__ Lpart) {
    __shared__ ushort plds[32][72];
    const int lane = threadIdx.x;
    const int row16 = lane & 15, grp = lane >> 4;
    const int qtile = 127 - blockIdx.x;          // reversed: biggest work first
    const int s = blockIdx.y;
    const int b = blockIdx.z;
    const int qt0 = qtile * 32;
    const int ext_tiles = (qt0 + 32 + 63) >> 6;
    const int t0 = (s * ext_tiles) >> 2;
    const int t1 = ((s + 1) * ext_tiles) >> 2;

    const size_t pbase = (((size_t)b * 128 + qtile) * 4 + s);
    float* mlM = Mpart + pbase * 32;
    float* mlL = Lpart + pbase * 32;

    if (t0 >= t1) {
        if (lane < 32) { mlM[lane] = -1e30f; mlL[lane] = 0.f; }
        return;
    }

    const ushort* qb = Qm + ((size_t)(b * 4096 + qt0 + row16)) * 128 + grp * 8;
    short8 qf[2][4];
#pragma unroll
    for (int rt = 0; rt < 2; ++rt)
#pragma unroll
        for (int kk = 0; kk < 4; ++kk)
            qf[rt][kk] = *reinterpret_cast<const short8*>(qb + rt * 16 * 128 + kk * 32);

    float4v o[2][8];
#pragma unroll
    for (int rt = 0; rt < 2; ++rt)
#pragma unroll
        for (int dt = 0; dt < 8; ++dt) o[rt][dt] = (float4v){0.f, 0.f, 0.f, 0.f};
    float mrun[2][4], lrun[2][4];
#pragma unroll
    for (int rt = 0; rt < 2; ++rt)
#pragma unroll
        for (int i = 0; i < 4; ++i) { mrun[rt][i] = -1e30f; lrun[rt][i] = 0.f; }

    const ushort* kbase = Km + (size_t)b * 4096 * 128;
    const ushort* vbase = Vt + (size_t)b * 128 * 4096;

    for (int t = t0; t < t1; ++t) {
        const int kvt = t * 64;
        short8 kf[4][4];
#pragma unroll
        for (int ct = 0; ct < 4; ++ct) {
            const ushort* kr = kbase + (size_t)(kvt + ct * 16 + row16) * 128 + grp * 8;
#pragma unroll
            for (int kk = 0; kk < 4; ++kk)
                kf[ct][kk] = *reinterpret_cast<const short8*>(kr + kk * 32);
        }
        float4v a[2][4];
#pragma unroll
        for (int rt = 0; rt < 2; ++rt)
#pragma unroll
            for (int ct = 0; ct < 4; ++ct) a[rt][ct] = (float4v){0.f, 0.f, 0.f, 0.f};
#pragma unroll
        for (int ct = 0; ct < 4; ++ct)
#pragma unroll
            for (int kk = 0; kk < 4; ++kk) {
                a[0][ct] = __builtin_amdgcn_mfma_f32_16x16x32_bf16(qf[0][kk], kf[ct][kk], a[0][ct], 0, 0, 0);
                a[1][ct] = __builtin_amdgcn_mfma_f32_16x16x32_bf16(qf[1][kk], kf[ct][kk], a[1][ct], 0, 0, 0);
            }
        short8 vf[2][8];
#pragma unroll
        for (int kk2 = 0; kk2 < 2; ++kk2)
#pragma unroll
            for (int dt = 0; dt < 8; ++dt)
                vf[kk2][dt] = *reinterpret_cast<const short8*>(
                    vbase + (size_t)(dt * 16 + row16) * 4096 + kvt + kk2 * 32 + grp * 8);

        float sc[2][4][4];
#pragma unroll
        for (int rt = 0; rt < 2; ++rt)
#pragma unroll
            for (int ct = 0; ct < 4; ++ct)
#pragma unroll
                for (int i = 0; i < 4; ++i) sc[rt][ct][i] = a[rt][ct][i] * 0.03125f;

        if (kvt + 63 > qt0) {
#pragma unroll
            for (int ct = 0; ct < 4; ++ct) {
                int kcol = kvt + ct * 16 + row16;
#pragma unroll
                for (int rt = 0; rt < 2; ++rt)
#pragma unroll
                    for (int i = 0; i < 4; ++i) {
                        int q = qt0 + rt * 16 + grp * 4 + i;
                        if (kcol > q) sc[rt][ct][i] = -3e38f;
                    }
            }
        }
        float scale_f[2][4];
#pragma unroll
        for (int rt = 0; rt < 2; ++rt)
#pragma unroll
            for (int i = 0; i < 4; ++i) {
                float tm = fmaxf(fmaxf(sc[rt][0][i], sc[rt][1][i]), fmaxf(sc[rt][2][i], sc[rt][3][i]));
#pragma unroll
                for (int msk = 1; msk < 16; msk <<= 1) tm = fmaxf(tm, __shfl_xor(tm, msk));
                float mnew = fmaxf(fmaxf(mrun[rt][i], tm), -1e30f);
                scale_f[rt][i] = __expf(mrun[rt][i] - mnew);
                float psum = 0.f;
#pragma unroll
                for (int ct = 0; ct < 4; ++ct) {
                    float p = __expf(sc[rt][ct][i] - mnew);
                    sc[rt][ct][i] = p;
                    psum += p;
                }
#pragma unroll
                for (int msk = 1; msk < 16; msk <<= 1) psum += __shfl_xor(psum, msk);
                lrun[rt][i] = lrun[rt][i] * scale_f[rt][i] + psum;
                mrun[rt][i] = mnew;
            }
#pragma unroll
        for (int rt = 0; rt < 2; ++rt)
#pragma unroll
            for (int dt = 0; dt < 8; ++dt)
#pragma unroll
                for (int i = 0; i < 4; ++i) o[rt][dt][i] *= scale_f[rt][i];
#pragma unroll
        for (int rt = 0; rt < 2; ++rt)
#pragma unroll
            for (int ct = 0; ct < 4; ++ct)
#pragma unroll
                for (int i = 0; i < 4; ++i)
                    plds[rt * 16 + grp * 4 + i][ct * 16 + row16] = f2bf(sc[rt][ct][i]);
        __syncthreads();
#pragma unroll
        for (int kk2 = 0; kk2 < 2; ++kk2) {
            short8 pa0 = *reinterpret_cast<const short8*>(&plds[row16][kk2 * 32 + grp * 8]);
            short8 pa1 = *reinterpret_cast<const short8*>(&plds[16 + row16][kk2 * 32 + grp * 8]);
#pragma unroll
            for (int dt = 0; dt < 8; ++dt) {
                o[0][dt] = __builtin_amdgcn_mfma_f32_16x16x32_bf16(pa0, vf[kk2][dt], o[0][dt], 0, 0, 0);
                o[1][dt] = __builtin_amdgcn_mfma_f32_16x16x32_bf16(pa1, vf[kk2][dt], o[1][dt], 0, 0, 0);
            }
        }
        __syncthreads();
    }
    float* ob = Opart + pbase * 32 * 128;
#pragma unroll
    for (int rt = 0; rt < 2; ++rt)
#pragma unroll
        for (int i = 0; i < 4; ++i) {
            int r = rt * 16 + grp * 4 + i;
#pragma unroll
            for (int dt = 0; dt < 8; ++dt)
                ob[(size_t)r * 128 + dt * 16 + row16] = o[rt][dt][i];
        }
    if (row16 == 0) {
#pragma unroll
        for (int rt = 0; rt < 2; ++rt)
#pragma unroll
            for (int i = 0; i < 4; ++i) {
                mlM[rt * 16 + grp * 4 + i] = mrun[rt][i];
                mlL[rt * 16 + grp * 4 + i] = lrun[rt][i];
            }
    }
}

// ---------------- combine the 4 KV splits (LSE merge) ----------------
__global__ __launch_bounds__(128) void attn_combine(const float* __restrict__ Opart,
                                                    const float* __restrict__ Mpart,
                                                    const float* __restrict__ Lpart,
                                                    ushort* __restrict__ AO) {
    const int row = blockIdx.x;
    const int b = row >> 12, t = row & 4095;
    const int qtile = t >> 5, r = t & 31;
    const size_t sb = (((size_t)b * 128 + qtile) * 4);
    float m[4], l[4];
#pragma unroll
    for (int s = 0; s < 4; ++s) {
        m[s] = Mpart[(sb + s) * 32 + r];
        l[s] = Lpart[(sb + s) * 32 + r];
    }
    float M = fmaxf(fmaxf(m[0], m[1]), fmaxf(m[2], m[3]));
    float w[4], denom = 0.f;
#pragma unroll
    for (int s = 0; s < 4; ++s) {
        w[s] = __expf(m[s] - M);
        denom += w[s] * l[s];
    }
    const int col = threadIdx.x;
    float acc = 0.f;
#pragma unroll
    for (int s = 0; s < 4; ++s) {
        if (w[s] > 0.f)
            acc += w[s] * Opart[((sb + s) * 32 + r) * 128 + col];
    }
    AO[(size_t)row * 128 + col] = f2bf(acc / denom);
}

// ---------------- GEMM2: out = AO @ w_out + b_out (tiled) ----------------
__global__ __launch_bounds__(256) void gemm_out(const ushort* __restrict__ AO,
                                                const ushort* __restrict__ wT,
                                                const float* __restrict__ bias,
                                                float* __restrict__ out) {
    __shared__ ushort As[128 * 64];
    __shared__ ushort Bs[128 * 64];
    const int tid = threadIdx.x;
    const int lane = tid & 63, w = tid >> 6;
    const int row16 = lane & 15, grp = lane >> 4;
    const int wr = w >> 1, wc = w & 1;
    const int mt = blockIdx.x * 128;
    const int n0 = blockIdx.y * 128;

    float4v acc[4][4];
#pragma unroll
    for (int m = 0; m < 4; ++m)
#pragma unroll
        for (int n = 0; n < 4; ++n) acc[m][n] = (float4v){0.f, 0.f, 0.f, 0.f};

#pragma unroll
    for (int kt = 0; kt < 128; kt += 64) {
        stage128x64(AO + (size_t)mt * 128 + kt, 128, As, tid);
        stage128x64(wT + (size_t)n0 * 128 + kt, 128, Bs, tid);
        __syncthreads();
        compute64(As, Bs, wr, wc, row16, grp, acc);
        __syncthreads();
    }

#pragma unroll
    for (int n = 0; n < 4; ++n) {
        int col = n0 + wc * 64 + n * 16 + row16;
        float bv = bias[col];
#pragma unroll
        for (int m = 0; m < 4; ++m)
#pragma unroll
            for (int i = 0; i < 4; ++i) {
                int row = mt + wr * 64 + m * 16 + grp * 4 + i;
                out[(size_t)row * 1024 + col] = acc[m][n][i] + bv;
            }
    }
}

extern "C" void kernel_launch(void* const* d_in, const int* in_sizes, int n_in,
                              void* d_out, int out_size, void* d_ws, size_t ws_size,
                              hipStream_t stream) {
    const float* x     = (const float*)d_in[0];   // [4,4096,1024]
    const float* w_qkv = (const float*)d_in[1];   // [1024,384]
    const float* w_out = (const float*)d_in[2];   // [128,1024]
    const float* b_out = (const float*)d_in[3];   // [1024]
    float* out = (float*)d_out;

    char* ws = (char*)d_ws;
    ushort* xb    = (ushort*)(ws);                 // 33,554,432 B (dead after gemm_qkv)
    ushort* wqkvT = (ushort*)(ws + 33554432);      //    786,432 B
    ushort* woutT = (ushort*)(ws + 34340864);      //    262,144 B
    ushort* Qm    = (ushort*)(ws + 34603008);      //  4,194,304 B
    ushort* Km    = (ushort*)(ws + 38797312);      //  4,194,304 B
    ushort* Vt    = (ushort*)(ws + 42991616);      //  4,194,304 B
    ushort* AO    = (ushort*)(ws + 47185920);      //  4,194,304 B (also Vrow, disjoint lifetime)
    float* Opart  = (float*)(ws);                  // alias xb (xb dead by attn_split)
    float* Mpart  = (float*)(ws + 51380224);       //    262,144 B
    float* Lpart  = (float*)(ws + 51642368);       //    262,144 B
    ushort* Vrow  = AO;

    {
        int n4 = (4 * 4096 * 1024) / 4;
        cast_f32_bf16<<<dim3((n4 + 255) / 256), dim3(256), 0, stream>>>(x, xb, n4);
    }
    transpose_cast<<<dim3((1024 * 384 + 255) / 256), dim3(256), 0, stream>>>(w_qkv, wqkvT, 1024, 384);
    transpose_cast<<<dim3((128 * 1024 + 255) / 256), dim3(256), 0, stream>>>(w_out, woutT, 128, 1024);

    // QKV projection (tiled, LDS-staged)
    gemm_qkv<<<dim3(128, 3), dim3(256), 0, stream>>>(xb, wqkvT, Qm, Km, Vrow);

    // V transpose for PV B-operand
    v_transpose<<<dim3(128, 4, 4), dim3(256), 0, stream>>>(Vrow, Vt);

    // causal flash attention, 4-way KV split + combine
    attn_split<<<dim3(128, 4, 4), dim3(64), 0, stream>>>(Qm, Km, Vt, Opart, Mpart, Lpart);
    attn_combine<<<dim3(16384), dim3(128), 0, stream>>>(Opart, Mpart, Lpart, AO);

    // output projection + bias (tiled)
    gemm_out<<<dim3(128, 8), dim3(256), 0, stream>>>(AO, woutT, b_out, out);
}